// Round 1
// baseline (614.578 us; speedup 1.0000x reference)
//
#include <hip/hip_runtime.h>
#include <math.h>

// Problem: SGConv — out[b,t,o] = bias[o] + sum_k (x_flat @ cheb_poly_k) @ W_k
// Key structure: cheb polys couple only |dt|<=2 in time; all blocks closed-form
// from sigmoid(adj_param), except the scalar sigma = ||lap||_2 (Lanczos on L^T L).
//
// ws layout (floats): M[128][5][16][16] at 0 (163840 floats), c=2/sigma at 163840.

#define KL 160          // Lanczos steps
#define C_OFF 163840    // float index of c in workspace

__device__ __forceinline__ float blk_reduce_512(float v, float* red, float* slot) {
  #pragma unroll
  for (int off = 32; off >= 1; off >>= 1) v += __shfl_down(v, off);
  const int lane = threadIdx.x & 63, wid = threadIdx.x >> 6;
  if (lane == 0) red[wid] = v;
  __syncthreads();
  if (threadIdx.x == 0) {
    float s = 0.f;
    #pragma unroll
    for (int i = 0; i < 8; i++) s += red[i];
    *slot = s;
  }
  __syncthreads();
  return *slot;
}

// ---------------- Kernel 1: sigma = ||lap||_2 via Lanczos on L^T L ----------------
__global__ __launch_bounds__(512) void k1_sigma(const float* __restrict__ adj,
                                                float* __restrict__ wsf) {
  __shared__ float Bsh[256];
  __shared__ float dis_i[16], dis_b[16];
  __shared__ float buf0[2048], buf1[2048], buf2[2048], bufY[2048], bufW[2048];
  __shared__ float red[8];
  __shared__ float slot[1];
  __shared__ float alphas[KL], betas[KL];

  const int tid = threadIdx.x;
  if (tid < 256) {
    const int f = tid >> 4, g = tid & 15;
    const float a = adj[tid];
    const float s = 1.f / (1.f + expf(-a));
    Bsh[tid] = (f == g) ? 1.f : s;   // B = feat + I (adj block incl. self-loop)
  }
  __syncthreads();
  if (tid < 16) {
    float rsum = 0.f;
    for (int j = 0; j < 16; j++) rsum += Bsh[tid * 16 + j];
    // d(t,f) = rowsum(B) + #temporal_neighbors  (rowsum(B) = 1 + sum feat)
    dis_i[tid] = 1.f / sqrtf(rsum + 2.f);  // interior t
    dis_b[tid] = 1.f / sqrtf(rsum + 1.f);  // t in {0,127}
  }
  __syncthreads();

  const int f = tid & 15;
  float Brow[16], Bcol[16];
  #pragma unroll
  for (int j = 0; j < 16; j++) { Brow[j] = Bsh[f * 16 + j]; Bcol[j] = Bsh[j * 16 + f]; }
  const float ui = dis_i[f], ub = dis_b[f];

  int rr[4], tt[4];
  float us[4];
  #pragma unroll
  for (int k = 0; k < 4; k++) {
    rr[k] = tid + 512 * k;
    tt[k] = rr[k] >> 4;
    us[k] = (tt[k] == 0 || tt[k] == 127) ? ub : ui;
  }

  float* pv = buf0;
  float* pvp = buf1;
  float* pz = buf2;

  // pseudo-random init vector
  #pragma unroll
  for (int k = 0; k < 4; k++) {
    unsigned h = (unsigned)rr[k] * 2654435761u;
    h ^= h >> 16; h *= 2246822519u; h ^= h >> 13;
    pv[rr[k]] = (float)(h & 0xFFFF) / 32768.f - 1.f;
    pvp[rr[k]] = 0.f;
  }
  {
    float pn = 0.f;
    #pragma unroll
    for (int k = 0; k < 4; k++) pn += pv[rr[k]] * pv[rr[k]];
    const float nn = blk_reduce_512(pn, red, slot);
    const float sc = rsqrtf(nn);
    #pragma unroll
    for (int k = 0; k < 4; k++) pv[rr[k]] *= sc;
  }
  __syncthreads();

  float beta_prev = 0.f;
  for (int it = 0; it < KL; it++) {
    // w = u .* v
    #pragma unroll
    for (int k = 0; k < 4; k++) bufW[rr[k]] = us[k] * pv[rr[k]];
    __syncthreads();
    // y = L v = v - u .* (A (u .* v))
    #pragma unroll
    for (int k = 0; k < 4; k++) {
      const int r = rr[k], t = tt[k];
      const float4* w4 = (const float4*)(bufW + (r - f));
      const float4 a0 = w4[0], a1 = w4[1], a2 = w4[2], a3 = w4[3];
      float s = a0.x*Brow[0]+a0.y*Brow[1]+a0.z*Brow[2]+a0.w*Brow[3]
              + a1.x*Brow[4]+a1.y*Brow[5]+a1.z*Brow[6]+a1.w*Brow[7]
              + a2.x*Brow[8]+a2.y*Brow[9]+a2.z*Brow[10]+a2.w*Brow[11]
              + a3.x*Brow[12]+a3.y*Brow[13]+a3.z*Brow[14]+a3.w*Brow[15];
      if (t > 0)   s += bufW[r - 16];
      if (t < 127) s += bufW[r + 16];
      bufY[r] = pv[r] - us[k] * s;
    }
    __syncthreads();
    // w = u .* y
    #pragma unroll
    for (int k = 0; k < 4; k++) bufW[rr[k]] = us[k] * bufY[rr[k]];
    __syncthreads();
    // z = L^T y  (A^T block uses B columns)
    #pragma unroll
    for (int k = 0; k < 4; k++) {
      const int r = rr[k], t = tt[k];
      const float4* w4 = (const float4*)(bufW + (r - f));
      const float4 a0 = w4[0], a1 = w4[1], a2 = w4[2], a3 = w4[3];
      float s = a0.x*Bcol[0]+a0.y*Bcol[1]+a0.z*Bcol[2]+a0.w*Bcol[3]
              + a1.x*Bcol[4]+a1.y*Bcol[5]+a1.z*Bcol[6]+a1.w*Bcol[7]
              + a2.x*Bcol[8]+a2.y*Bcol[9]+a2.z*Bcol[10]+a2.w*Bcol[11]
              + a3.x*Bcol[12]+a3.y*Bcol[13]+a3.z*Bcol[14]+a3.w*Bcol[15];
      if (t > 0)   s += bufW[r - 16];
      if (t < 127) s += bufW[r + 16];
      pz[r] = bufY[r] - us[k] * s;
    }
    // alpha = v . z   (own rows only -> no extra sync needed; reduce has barriers)
    float pa = 0.f;
    #pragma unroll
    for (int k = 0; k < 4; k++) pa += pv[rr[k]] * pz[rr[k]];
    const float alpha = blk_reduce_512(pa, red, slot);
    float pn = 0.f;
    #pragma unroll
    for (int k = 0; k < 4; k++) {
      const float z = pz[rr[k]] - alpha * pv[rr[k]] - beta_prev * pvp[rr[k]];
      pz[rr[k]] = z;
      pn += z * z;
    }
    const float b2 = blk_reduce_512(pn, red, slot);
    const float beta = sqrtf(b2);
    if (tid == 0) { alphas[it] = alpha; betas[it] = beta; }
    const float rb = (beta > 1e-25f) ? (1.f / beta) : 0.f;
    #pragma unroll
    for (int k = 0; k < 4; k++) pz[rr[k]] *= rb;
    float* tmp = pvp; pvp = pv; pv = pz; pz = tmp;
    beta_prev = beta;
    __syncthreads();
  }

  // lambda_max of tridiagonal T via 64-lane parallel bisection (Sturm counts)
  if (tid < 64) {
    float lo = -1e30f, hi = -1e30f;
    for (int j = tid; j < KL; j += 64) {
      const float a = alphas[j];
      const float bl = (j > 0) ? betas[j - 1] : 0.f;
      const float br = (j < KL - 1) ? betas[j] : 0.f;
      lo = fmaxf(lo, a);                          // lambda_max >= max diag
      hi = fmaxf(hi, a + fabsf(bl) + fabsf(br));  // Gershgorin
    }
    #pragma unroll
    for (int off = 32; off >= 1; off >>= 1) {
      lo = fmaxf(lo, __shfl_down(lo, off));
      hi = fmaxf(hi, __shfl_down(hi, off));
    }
    lo = __shfl(lo, 0); hi = __shfl(hi, 0);
    for (int round = 0; round < 12; round++) {
      const float lam = lo + (hi - lo) * (float)(tid + 1) / 65.f;
      int cnt = 0;
      float d = alphas[0] - lam;
      if (d < 0.f) cnt++;
      for (int i = 1; i < KL; i++) {
        const float b = betas[i - 1];
        if (fabsf(d) < 1e-30f) d = (d < 0.f ? -1e-30f : 1e-30f);
        const float dn = (alphas[i] - lam) - b * b / d;
        if (dn < 0.f) cnt++;
        d = dn;
      }
      const unsigned long long mask = __ballot(cnt >= KL);
      if (mask == 0ull) {
        lo = lo + (hi - lo) * 64.f / 65.f;
      } else {
        const int l = (int)__builtin_ctzll(mask);
        const float nhi = lo + (hi - lo) * (float)(l + 1) / 65.f;
        const float nlo = (l == 0) ? lo : lo + (hi - lo) * (float)l / 65.f;
        hi = nhi; lo = nlo;
      }
    }
    if (tid == 0) {
      const float lam = 0.5f * (lo + hi);
      const float sigma = sqrtf(fmaxf(lam, 1e-30f));
      wsf[C_OFF] = 2.f / sigma;
    }
  }
}

// ---------------- Kernel 2: build banded fused operator M[t][dt][f][o] ----------------
__global__ __launch_bounds__(256) void k2_build(const float* __restrict__ adj,
                                                const float* __restrict__ W,
                                                float* __restrict__ wsf) {
  const int t = blockIdx.x;
  const int tid = threadIdx.x;
  __shared__ float Bsh[256], Wsh[768];
  __shared__ float Dm[256], D0[256], Dp[256], DD[256];
  __shared__ float dis_i[16], dis_b[16], csh[1];

  {
    const int f = tid >> 4, g = tid & 15;
    const float a = adj[tid];
    const float s = 1.f / (1.f + expf(-a));
    Bsh[tid] = (f == g) ? 1.f : s;
    Wsh[tid] = W[tid];
    Wsh[tid + 256] = W[tid + 256];
    Wsh[tid + 512] = W[tid + 512];
    if (tid == 0) csh[0] = wsf[C_OFF];
  }
  __syncthreads();
  if (tid < 16) {
    float rsum = 0.f;
    for (int j = 0; j < 16; j++) rsum += Bsh[tid * 16 + j];
    dis_i[tid] = 1.f / sqrtf(rsum + 2.f);
    dis_b[tid] = 1.f / sqrtf(rsum + 1.f);
  }
  __syncthreads();
  const float c = csh[0];
  const int r = tid >> 4, q = tid & 15;

  auto uat = [&](int a_, int ff) -> float {
    return (a_ == 0 || a_ == 127) ? dis_b[ff] : dis_i[ff];
  };

  // Ls diagonal blocks: D_a[f,f'] = (c-1) delta - c u_a(f) u_a(f') B[f,f']
  D0[tid] = ((r == q) ? (c - 1.f) : 0.f) - c * uat(t, r) * uat(t, q) * Bsh[tid];
  if (t > 0)   Dm[tid] = ((r == q) ? (c - 1.f) : 0.f) - c * uat(t - 1, r) * uat(t - 1, q) * Bsh[tid];
  if (t < 127) Dp[tid] = ((r == q) ? (c - 1.f) : 0.f) - c * uat(t + 1, r) * uat(t + 1, q) * Bsh[tid];
  __syncthreads();
  {
    float s = 0.f;
    #pragma unroll
    for (int k = 0; k < 16; k++) s += D0[r * 16 + k] * D0[k * 16 + q];
    DD[tid] = s;  // D_t^2
  }
  __syncthreads();

  const int fo = r;   // input feature f (row of P block at time t+dt)
  const int o = q;    // output channel
  float m[5];
  const float ut_f = uat(t, fo);

  // dt = 0:  W0 + D_t W1 + (2 D_t^2 + diag(2 c^2 u_t^2 (u_{t-1}^2 + u_{t+1}^2)) - I) W2
  {
    float acc = Wsh[fo * 16 + o];
    const float diag0 = 2.f * c * c * ut_f * ut_f *
                        ((t > 0 ? uat(t - 1, fo) * uat(t - 1, fo) : 0.f) +
                         (t < 127 ? uat(t + 1, fo) * uat(t + 1, fo) : 0.f)) - 1.f;
    #pragma unroll
    for (int fp = 0; fp < 16; fp++) {
      acc += D0[fo * 16 + fp] * Wsh[256 + fp * 16 + o];
      const float p2 = 2.f * DD[fo * 16 + fp] + ((fo == fp) ? diag0 : 0.f);
      acc += p2 * Wsh[512 + fp * 16 + o];
    }
    m[2] = acc;
  }
  // dt = +1: P1 = diag(g), P2 = 2(g(f) D_t + D_{t+1} g(f')),  g = -c u_{t+1} u_t
  if (t < 127) {
    const float gf = -c * uat(t + 1, fo) * ut_f;
    float acc = gf * Wsh[256 + fo * 16 + o];
    #pragma unroll
    for (int fp = 0; fp < 16; fp++) {
      const float gq = -c * uat(t + 1, fp) * uat(t, fp);
      const float p2 = 2.f * (gf * D0[fo * 16 + fp] + Dp[fo * 16 + fp] * gq);
      acc += p2 * Wsh[512 + fp * 16 + o];
    }
    m[3] = acc;
  } else m[3] = 0.f;
  // dt = -1
  if (t > 0) {
    const float gf = -c * uat(t - 1, fo) * ut_f;
    float acc = gf * Wsh[256 + fo * 16 + o];
    #pragma unroll
    for (int fp = 0; fp < 16; fp++) {
      const float gq = -c * uat(t - 1, fp) * uat(t, fp);
      const float p2 = 2.f * (Dm[fo * 16 + fp] * gq + gf * D0[fo * 16 + fp]);
      acc += p2 * Wsh[512 + fp * 16 + o];
    }
    m[1] = acc;
  } else m[1] = 0.f;
  // dt = +/-2: diagonal 2 c^2 u_{t+-2} u_{t+-1}^2 u_t
  m[4] = (t < 126) ? (2.f * c * c * uat(t + 2, fo) * uat(t + 1, fo) * uat(t + 1, fo) * ut_f
                      * Wsh[512 + fo * 16 + o]) : 0.f;
  m[0] = (t > 1) ? (2.f * c * c * uat(t - 2, fo) * uat(t - 1, fo) * uat(t - 1, fo) * ut_f
                    * Wsh[512 + fo * 16 + o]) : 0.f;

  #pragma unroll
  for (int d5 = 0; d5 < 5; d5++)
    wsf[((size_t)(t * 5 + d5) * 16 + fo) * 16 + o] = m[d5];
}

// ---------------- Kernel 3: out[b,t,o] = bias + sum_{dt,f} x[b,t+dt,f] M[t][dt][f][o] ----
__global__ __launch_bounds__(256) void k3_main(const float* __restrict__ x,
                                               const float* __restrict__ bias,
                                               const float* __restrict__ wsf,
                                               float* __restrict__ out) {
  const int tg = blockIdx.y, bg = blockIdx.x;
  const int t0 = tg * 16, b0 = bg * 16;
  const int tid = threadIdx.x;
  const int tl = tid >> 4, o = tid & 15;
  const int t = t0 + tl;

  float M[80];  // M column for this (t,o): [dt][f]
  {
    const float* Mt = wsf + (size_t)t * 5 * 256;
    #pragma unroll
    for (int i = 0; i < 80; i++) M[i] = Mt[i * 16 + o];
  }
  const float bo = bias[o];

  __shared__ float xs[1600];  // 4 batches x 20 rows x (16+4 pad) floats

  for (int cc = 0; cc < 4; cc++) {
    __syncthreads();
    for (int idx = tid; idx < 320; idx += 256) {
      const int cb = idx / 80, rem = idx % 80;
      const int rrow = rem >> 2, qq = rem & 3;
      int gr = t0 - 2 + rrow;
      gr = gr < 0 ? 0 : (gr > 127 ? 127 : gr);  // clamped rows hit M==0 entries
      const float4 v = *(const float4*)(x + ((size_t)(b0 + cc * 4 + cb) * 128 + gr) * 16 + qq * 4);
      *(float4*)(xs + cb * 400 + rrow * 20 + qq * 4) = v;
    }
    __syncthreads();
    #pragma unroll
    for (int cb = 0; cb < 4; cb++) {
      float acc0 = bo, acc1 = 0.f;
      #pragma unroll
      for (int dt = 0; dt < 5; dt++) {
        const float* xr = xs + cb * 400 + (tl + dt) * 20;
        const float4 xa = *(const float4*)(xr);
        const float4 xb = *(const float4*)(xr + 4);
        const float4 xc = *(const float4*)(xr + 8);
        const float4 xd = *(const float4*)(xr + 12);
        const float* Mp = M + dt * 16;
        acc0 += xa.x * Mp[0] + xa.y * Mp[1] + xa.z * Mp[2] + xa.w * Mp[3]
              + xb.x * Mp[4] + xb.y * Mp[5] + xb.z * Mp[6] + xb.w * Mp[7];
        acc1 += xc.x * Mp[8] + xc.y * Mp[9] + xc.z * Mp[10] + xc.w * Mp[11]
              + xd.x * Mp[12] + xd.y * Mp[13] + xd.z * Mp[14] + xd.w * Mp[15];
      }
      out[((size_t)(b0 + cc * 4 + cb) * 128 + t) * 16 + o] = acc0 + acc1;
    }
  }
}

extern "C" void kernel_launch(void* const* d_in, const int* in_sizes, int n_in,
                              void* d_out, int out_size, void* d_ws, size_t ws_size,
                              hipStream_t stream) {
  const float* x    = (const float*)d_in[0];  // [1024,128,16]
  const float* W    = (const float*)d_in[1];  // [3,16,16]
  const float* bias = (const float*)d_in[2];  // [16]
  const float* adj  = (const float*)d_in[3];  // [16,16]
  float* out = (float*)d_out;
  float* wsf = (float*)d_ws;  // needs 163841 floats (~656 KB)

  k1_sigma<<<dim3(1), dim3(512), 0, stream>>>(adj, wsf);
  k2_build<<<dim3(128), dim3(256), 0, stream>>>(adj, W, wsf);
  k3_main<<<dim3(64, 8), dim3(256), 0, stream>>>(x, bias, wsf, out);
}

// Round 3
// 146.754 us; speedup vs baseline: 4.1878x; 4.1878x over previous
//
#include <hip/hip_runtime.h>
#include <math.h>

// SGConv: out[b,t,o] = bias[o] + sum_k (x_flat @ cheb_k) @ W_k.
// cheb polys couple only |dt|<=2; all blocks closed-form from sigmoid(adj).
// sigma = ||lap||_2 (LARGEST SINGULAR VALUE — lap is asymmetric!).
// Uniform-degree tensor structure: lap_u = sum_k s_k s_k^T (x) G_k,
// G_k = I - mu_k diag(u^2) - uBu  (16x16, asymmetric), mu_k = 2cos(k pi/129).
// => sigma = max_k sigma_max(G_k); sigma_max(G_mu)^2 convex in mu => endpoints
// mu = -+2cos(pi/129) only. Per endpoint: H = G^T G, lambda_max via exact
// 16-lane reorthogonalized Lanczos + Sturm bisection. Boundary-degree
// correction is O(1e-3) relative — below error budget.
//
// ws layout (floats): M[128][5][16][16] at 0 (163840 floats).

#define MU_MIN (-1.99940694f)   // -2*cos(pi/129)

__device__ __forceinline__ float dot16(float x) {  // sum over lanes 0..15
  x += __shfl_xor(x, 1);
  x += __shfl_xor(x, 2);
  x += __shfl_xor(x, 4);
  x += __shfl_xor(x, 8);
  return x;
}

// ---------------- Kernel A: sigma (reduced, exact) + banded fused operator M ----------------
__global__ __launch_bounds__(256) void kA_build(const float* __restrict__ adj,
                                                const float* __restrict__ W,
                                                float* __restrict__ wsf) {
  const int t = blockIdx.x;
  const int tid = threadIdx.x;
  __shared__ float Bsh[256], Wsh[768];
  __shared__ float Dm[256], D0[256], Dp[256], DD[256];
  __shared__ float dis_i[16], dis_b[16], csh[1];
  __shared__ float Gsh[256], Hsh[256], Vsh[256], alsh[16], besh[16];
  __shared__ float lamsh[2];

  {
    const int f = tid >> 4, g = tid & 15;
    const float a = adj[tid];
    const float s = 1.f / (1.f + expf(-a));
    Bsh[tid] = (f == g) ? 1.f : s;     // B = feat + self-loop (ASYMMETRIC)
    Wsh[tid] = W[tid];
    Wsh[tid + 256] = W[tid + 256];
    Wsh[tid + 512] = W[tid + 512];
  }
  __syncthreads();
  if (tid < 16) {
    float rsum = 0.f;
    for (int j = 0; j < 16; j++) rsum += Bsh[tid * 16 + j];  // ROW sums (d = sum axis=1)
    dis_i[tid] = 1.f / sqrtf(rsum + 2.f);  // interior t
    dis_b[tid] = 1.f / sqrtf(rsum + 1.f);  // t in {0,127}
  }
  __syncthreads();

  // --- sigma via two endpoint blocks G = I - mu*diag(u^2) - uBu ---
  for (int pass = 0; pass < 2; pass++) {
    const float mu = (pass == 0) ? MU_MIN : -MU_MIN;
    {
      const int f = tid >> 4, g = tid & 15;
      float gv = -dis_i[f] * Bsh[f * 16 + g] * dis_i[g];
      if (f == g) gv += 1.f - mu * dis_i[f] * dis_i[f];
      Gsh[tid] = gv;
    }
    __syncthreads();
    {
      // H = G^T G  (symmetric PSD; note lambda_max(G^T G)=lambda_max(G G^T))
      const int r = tid >> 4, q = tid & 15;
      float s = 0.f;
      #pragma unroll
      for (int k = 0; k < 16; k++) s += Gsh[k * 16 + r] * Gsh[k * 16 + q];
      Hsh[tid] = s;
    }
    __syncthreads();

    // 16-lane Lanczos with full reorthogonalization: exact tridiag of H
    if (tid < 16) {
      const int f = tid;
      float Hrow[16];
      #pragma unroll
      for (int g = 0; g < 16; g++) Hrow[g] = Hsh[f * 16 + g];
      unsigned h = (unsigned)(f + 1) * 2654435761u;
      h ^= h >> 16; h *= 2246822519u; h ^= h >> 13;
      float v = (float)(h & 0xFFFF) / 65536.f + 0.0625f;
      v *= rsqrtf(dot16(v * v));
      float vp = 0.f, beta_prev = 0.f;
      int done = 0;
      for (int it = 0; it < 16; it++) {
        Vsh[it * 16 + f] = v;
        float w = 0.f;
        #pragma unroll
        for (int g = 0; g < 16; g++) w += Hrow[g] * Vsh[it * 16 + g];
        w -= beta_prev * vp;
        const float alpha = dot16(w * v);
        w -= alpha * v;
        for (int j = 0; j <= it; j++) {           // full reorth
          const float pr = dot16(w * Vsh[j * 16 + f]);
          w -= pr * Vsh[j * 16 + f];
        }
        const float beta = sqrtf(dot16(w * w));
        if (f == 0) { alsh[it] = alpha; besh[it] = beta; }
        if (beta < 1e-6f) { done = it + 1; break; }
        vp = v; v = w / beta; beta_prev = beta;
      }
      if (f == 0 && done) {   // breakdown: pad spectrum BELOW lam_max (H PSD)
        besh[done - 1] = 0.f;
        for (int it = done; it < 16; it++) { alsh[it] = 0.f; besh[it] = 0.f; }
      }
    }
    __syncthreads();

    // 64-lane Sturm bisection for lambda_max of the 16x16 tridiagonal
    if (tid < 64) {
      float dg = -1e30f, ra = -1e30f;
      if (tid < 16) {
        dg = Hsh[tid * 16 + tid];
        ra = 0.f;
        #pragma unroll
        for (int q = 0; q < 16; q++) ra += fabsf(Hsh[tid * 16 + q]);
      }
      #pragma unroll
      for (int off = 32; off >= 1; off >>= 1) {
        dg = fmaxf(dg, __shfl_xor(dg, off));
        ra = fmaxf(ra, __shfl_xor(ra, off));
      }
      float lo = dg;                         // lam_max >= max diag
      float hi = ra + 1e-5f + 1e-5f * ra;    // Gershgorin upper
      for (int round = 0; round < 4; round++) {
        const float lam = lo + (hi - lo) * (float)(tid + 1) / 65.f;
        int cnt = 0;
        float d = alsh[0] - lam;
        if (d < 0.f) cnt++;
        #pragma unroll
        for (int i = 1; i < 16; i++) {
          const float b = besh[i - 1];
          if (fabsf(d) < 1e-30f) d = (d < 0.f ? -1e-30f : 1e-30f);
          const float dn = (alsh[i] - lam) - b * b / d;
          if (dn < 0.f) cnt++;
          d = dn;
        }
        const unsigned long long mask = __ballot(cnt >= 16);  // all eigs < lam
        if (mask == 0ull) {
          lo = lo + (hi - lo) * 64.f / 65.f;
        } else {
          const int l = (int)__builtin_ctzll(mask);
          const float nhi = lo + (hi - lo) * (float)(l + 1) / 65.f;
          const float nlo = (l == 0) ? lo : lo + (hi - lo) * (float)l / 65.f;
          hi = nhi; lo = nlo;
        }
      }
      if (tid == 0) lamsh[pass] = 0.5f * (lo + hi);
    }
    __syncthreads();
  }
  if (tid == 0) {
    const float lam = fmaxf(fmaxf(lamsh[0], lamsh[1]), 1e-20f);
    csh[0] = 2.f / sqrtf(lam);   // c = 2 / sigma
  }
  __syncthreads();

  const float c = csh[0];
  const int r = tid >> 4, q = tid & 15;

  auto uat = [&](int a_, int ff) -> float {
    return (a_ == 0 || a_ == 127) ? dis_b[ff] : dis_i[ff];
  };

  // Ls diagonal blocks: D_a[f,f'] = (c-1) delta - c u_a(f) u_a(f') B[f,f']
  D0[tid] = ((r == q) ? (c - 1.f) : 0.f) - c * uat(t, r) * uat(t, q) * Bsh[tid];
  if (t > 0)   Dm[tid] = ((r == q) ? (c - 1.f) : 0.f) - c * uat(t - 1, r) * uat(t - 1, q) * Bsh[tid];
  if (t < 127) Dp[tid] = ((r == q) ? (c - 1.f) : 0.f) - c * uat(t + 1, r) * uat(t + 1, q) * Bsh[tid];
  __syncthreads();
  {
    float s = 0.f;
    #pragma unroll
    for (int k = 0; k < 16; k++) s += D0[r * 16 + k] * D0[k * 16 + q];
    DD[tid] = s;  // D_t^2
  }
  __syncthreads();

  const int fo = r;   // input feature f (row of P block at time t+dt)
  const int o = q;    // output channel
  float m[5];
  const float ut_f = uat(t, fo);

  // dt = 0:  W0 + D_t W1 + (2 D_t^2 + diag(2 c^2 u_t^2 (u_{t-1}^2 + u_{t+1}^2)) - I) W2
  {
    float acc = Wsh[fo * 16 + o];
    const float diag0 = 2.f * c * c * ut_f * ut_f *
                        ((t > 0 ? uat(t - 1, fo) * uat(t - 1, fo) : 0.f) +
                         (t < 127 ? uat(t + 1, fo) * uat(t + 1, fo) : 0.f)) - 1.f;
    #pragma unroll
    for (int fp = 0; fp < 16; fp++) {
      acc += D0[fo * 16 + fp] * Wsh[256 + fp * 16 + o];
      const float p2 = 2.f * DD[fo * 16 + fp] + ((fo == fp) ? diag0 : 0.f);
      acc += p2 * Wsh[512 + fp * 16 + o];
    }
    m[2] = acc;
  }
  // dt = +1: P1 = diag(g), P2 = 2(g(f) D_t + D_{t+1} g(f')),  g = -c u_{t+1} u_t
  if (t < 127) {
    const float gf = -c * uat(t + 1, fo) * ut_f;
    float acc = gf * Wsh[256 + fo * 16 + o];
    #pragma unroll
    for (int fp = 0; fp < 16; fp++) {
      const float gq = -c * uat(t + 1, fp) * uat(t, fp);
      const float p2 = 2.f * (gf * D0[fo * 16 + fp] + Dp[fo * 16 + fp] * gq);
      acc += p2 * Wsh[512 + fp * 16 + o];
    }
    m[3] = acc;
  } else m[3] = 0.f;
  // dt = -1
  if (t > 0) {
    const float gf = -c * uat(t - 1, fo) * ut_f;
    float acc = gf * Wsh[256 + fo * 16 + o];
    #pragma unroll
    for (int fp = 0; fp < 16; fp++) {
      const float gq = -c * uat(t - 1, fp) * uat(t, fp);
      const float p2 = 2.f * (Dm[fo * 16 + fp] * gq + gf * D0[fo * 16 + fp]);
      acc += p2 * Wsh[512 + fp * 16 + o];
    }
    m[1] = acc;
  } else m[1] = 0.f;
  // dt = +/-2: diagonal 2 c^2 u_{t+-2} u_{t+-1}^2 u_t
  m[4] = (t < 126) ? (2.f * c * c * uat(t + 2, fo) * uat(t + 1, fo) * uat(t + 1, fo) * ut_f
                      * Wsh[512 + fo * 16 + o]) : 0.f;
  m[0] = (t > 1) ? (2.f * c * c * uat(t - 2, fo) * uat(t - 1, fo) * uat(t - 1, fo) * ut_f
                    * Wsh[512 + fo * 16 + o]) : 0.f;

  #pragma unroll
  for (int d5 = 0; d5 < 5; d5++)
    wsf[((size_t)(t * 5 + d5) * 16 + fo) * 16 + o] = m[d5];
}

// ---------------- Kernel 3: out[b,t,o] = bias + sum_{dt,f} x[b,t+dt,f] M[t][dt][f][o] ----
__global__ __launch_bounds__(256) void k3_main(const float* __restrict__ x,
                                               const float* __restrict__ bias,
                                               const float* __restrict__ wsf,
                                               float* __restrict__ out) {
  const int tg = blockIdx.y, bg = blockIdx.x;
  const int t0 = tg * 16, b0 = bg * 16;
  const int tid = threadIdx.x;
  const int tl = tid >> 4, o = tid & 15;
  const int t = t0 + tl;

  float M[80];  // M column for this (t,o): [dt][f]
  {
    const float* Mt = wsf + (size_t)t * 5 * 256;
    #pragma unroll
    for (int i = 0; i < 80; i++) M[i] = Mt[i * 16 + o];
  }
  const float bo = bias[o];

  __shared__ float xs[1600];  // 4 batches x 20 rows x (16+4 pad) floats

  for (int cc = 0; cc < 4; cc++) {
    __syncthreads();
    for (int idx = tid; idx < 320; idx += 256) {
      const int cb = idx / 80, rem = idx % 80;
      const int rrow = rem >> 2, qq = rem & 3;
      int gr = t0 - 2 + rrow;
      gr = gr < 0 ? 0 : (gr > 127 ? 127 : gr);  // clamped rows hit M==0 entries
      const float4 v = *(const float4*)(x + ((size_t)(b0 + cc * 4 + cb) * 128 + gr) * 16 + qq * 4);
      *(float4*)(xs + cb * 400 + rrow * 20 + qq * 4) = v;
    }
    __syncthreads();
    #pragma unroll
    for (int cb = 0; cb < 4; cb++) {
      float acc0 = bo, acc1 = 0.f;
      #pragma unroll
      for (int dt = 0; dt < 5; dt++) {
        const float* xr = xs + cb * 400 + (tl + dt) * 20;
        const float4 xa = *(const float4*)(xr);
        const float4 xb = *(const float4*)(xr + 4);
        const float4 xc = *(const float4*)(xr + 8);
        const float4 xd = *(const float4*)(xr + 12);
        const float* Mp = M + dt * 16;
        acc0 += xa.x * Mp[0] + xa.y * Mp[1] + xa.z * Mp[2] + xa.w * Mp[3]
              + xb.x * Mp[4] + xb.y * Mp[5] + xb.z * Mp[6] + xb.w * Mp[7];
        acc1 += xc.x * Mp[8] + xc.y * Mp[9] + xc.z * Mp[10] + xc.w * Mp[11]
              + xd.x * Mp[12] + xd.y * Mp[13] + xd.z * Mp[14] + xd.w * Mp[15];
      }
      out[((size_t)(b0 + cc * 4 + cb) * 128 + t) * 16 + o] = acc0 + acc1;
    }
  }
}

extern "C" void kernel_launch(void* const* d_in, const int* in_sizes, int n_in,
                              void* d_out, int out_size, void* d_ws, size_t ws_size,
                              hipStream_t stream) {
  const float* x    = (const float*)d_in[0];  // [1024,128,16]
  const float* W    = (const float*)d_in[1];  // [3,16,16]
  const float* bias = (const float*)d_in[2];  // [16]
  const float* adj  = (const float*)d_in[3];  // [16,16]
  float* out = (float*)d_out;
  float* wsf = (float*)d_ws;  // needs 163840 floats (~656 KB)

  kA_build<<<dim3(128), dim3(256), 0, stream>>>(adj, W, wsf);
  k3_main<<<dim3(64, 8), dim3(256), 0, stream>>>(x, bias, wsf, out);
}

// Round 4
// 85.297 us; speedup vs baseline: 7.2051x; 1.7205x over previous
//
#include <hip/hip_runtime.h>
#include <math.h>

// SGConv: out[b,t,o] = bias[o] + sum_k (x_flat @ cheb_k) @ W_k.
// cheb polys couple only |dt|<=2; all blocks closed-form from sigmoid(adj).
// sigma = ||lap||_2 (largest singular value; lap asymmetric).
// Uniform-degree tensor structure: sigma = max over endpoint mu = -+2cos(pi/129)
// of sigma_max(G_mu), G_mu = I - mu diag(u^2) - uBu (16x16). (sigma_max^2 convex
// in mu => endpoints only; boundary-degree correction O(1e-3) rel — in budget.)
// lam_max(H=G^T G) via 8 trace-normalized squarings (H^256) + one Rayleigh
// quotient — barrier-parallel, NO serial shuffle chains (R3's 73us lesson).
//
// ws layout (floats): M[128][5][16][16] at 0 (163840 floats).

#define MU_MIN (-1.99940694f)   // -2*cos(pi/129)

__device__ __forceinline__ float dot16(float x) {  // sum over lanes 0..15
  x += __shfl_xor(x, 1);
  x += __shfl_xor(x, 2);
  x += __shfl_xor(x, 4);
  x += __shfl_xor(x, 8);
  return x;
}

// ---------------- Kernel A: sigma (power-squaring) + banded fused operator M ----------------
__global__ __launch_bounds__(256) void kA_build(const float* __restrict__ adj,
                                                const float* __restrict__ W,
                                                float* __restrict__ wsf) {
  const int t = blockIdx.x;
  const int tid = threadIdx.x;
  __shared__ float Bsh[256], Wsh[768];
  __shared__ float Dm[256], D0[256], Dp[256], DD[256];
  __shared__ float dis_i[16], dis_b[16], csh[1];
  __shared__ float H0[512], Pbuf[512], Qbuf[512];
  __shared__ float scl[2], lamsh[2];
  __shared__ int jst[2];

  {
    const int f = tid >> 4, g = tid & 15;
    const float a = adj[tid];
    const float s = 1.f / (1.f + expf(-a));
    Bsh[tid] = (f == g) ? 1.f : s;     // B = feat + self-loop (asymmetric)
    Wsh[tid] = W[tid];
    Wsh[tid + 256] = W[tid + 256];
    Wsh[tid + 512] = W[tid + 512];
  }
  __syncthreads();
  if (tid < 16) {
    float rsum = 0.f;
    for (int j = 0; j < 16; j++) rsum += Bsh[tid * 16 + j];  // row sums (d = sum axis=1)
    dis_i[tid] = 1.f / sqrtf(rsum + 2.f);  // interior t
    dis_b[tid] = 1.f / sqrtf(rsum + 1.f);  // t in {0,127}
  }
  __syncthreads();

  // --- sigma: both endpoint passes concurrently (thread halves) ---
  const int pass = tid >> 7, idx = tid & 127;
  const int pb = pass * 256;
  const float mu = pass ? -MU_MIN : MU_MIN;
  // G into Pbuf
  for (int e = idx; e < 256; e += 128) {
    const int f = e >> 4, g = e & 15;
    float gv = -dis_i[f] * Bsh[e] * dis_i[g];
    if (f == g) gv += 1.f - mu * dis_i[f] * dis_i[f];
    Pbuf[pb + e] = gv;
  }
  __syncthreads();
  // H0 = G^T G (symmetric PSD); column reads broadcast across lanes (few r values)
  for (int e = idx; e < 256; e += 128) {
    const int r = e >> 4, q = e & 15;
    float s = 0.f;
    #pragma unroll
    for (int k = 0; k < 16; k++) s += Pbuf[pb + k * 16 + r] * Pbuf[pb + k * 16 + q];
    H0[pb + e] = s;
    Qbuf[pb + e] = s;
  }
  __syncthreads();

  float* cur = Qbuf;
  float* nxt = Pbuf;
  #pragma unroll 1
  for (int it = 0; it < 8; it++) {   // cur -> cur^2 / trace^2   (H^256 total)
    if (idx == 0) {
      float tr = 0.f;
      #pragma unroll
      for (int d = 0; d < 16; d++) tr += cur[pb + d * 17];
      scl[pass] = 1.f / (tr * tr);
    }
    __syncthreads();
    const float s2 = scl[pass];
    for (int e = idx; e < 256; e += 128) {
      const int r = e >> 4, q = e & 15;
      const float4* rr = (const float4*)(cur + pb + r * 16);  // symmetric: col q = row q
      const float4* qq = (const float4*)(cur + pb + q * 16);
      float s = 0.f;
      #pragma unroll
      for (int k4 = 0; k4 < 4; k4++) {
        const float4 a = rr[k4], b = qq[k4];
        s += a.x * b.x + a.y * b.y + a.z * b.z + a.w * b.w;
      }
      nxt[pb + e] = s * s2;
    }
    __syncthreads();
    float* tmp = cur; cur = nxt; nxt = tmp;
  }
  if (idx == 0) {   // dominant column = argmax diagonal of H^256
    int bj = 0; float bd = -1.f;
    #pragma unroll
    for (int d = 0; d < 16; d++) {
      const float v = cur[pb + d * 17];
      if (v > bd) { bd = v; bj = d; }
    }
    jst[pass] = bj;
  }
  __syncthreads();
  if (idx < 16) {   // one-shot Rayleigh quotient of v = Hhat[:,j*] against H0
    const int r = idx, js = jst[pass];
    const float vr = cur[pb + r * 16 + js];
    float hv = 0.f;
    #pragma unroll
    for (int q = 0; q < 16; q++) hv += H0[pb + r * 16 + q] * cur[pb + q * 16 + js];
    const float num = dot16(vr * hv);
    const float den = dot16(vr * vr);
    if (r == 0) lamsh[pass] = num / fmaxf(den, 1e-30f);
  }
  __syncthreads();
  if (tid == 0) {
    const float lam = fmaxf(fmaxf(lamsh[0], lamsh[1]), 1e-20f);
    csh[0] = 2.f / sqrtf(lam);   // c = 2 / sigma
  }
  __syncthreads();

  const float c = csh[0];
  const int r = tid >> 4, q = tid & 15;

  auto uat = [&](int a_, int ff) -> float {
    return (a_ == 0 || a_ == 127) ? dis_b[ff] : dis_i[ff];
  };

  // Ls diagonal blocks: D_a[f,f'] = (c-1) delta - c u_a(f) u_a(f') B[f,f']
  D0[tid] = ((r == q) ? (c - 1.f) : 0.f) - c * uat(t, r) * uat(t, q) * Bsh[tid];
  if (t > 0)   Dm[tid] = ((r == q) ? (c - 1.f) : 0.f) - c * uat(t - 1, r) * uat(t - 1, q) * Bsh[tid];
  if (t < 127) Dp[tid] = ((r == q) ? (c - 1.f) : 0.f) - c * uat(t + 1, r) * uat(t + 1, q) * Bsh[tid];
  __syncthreads();
  {
    float s = 0.f;
    #pragma unroll
    for (int k = 0; k < 16; k++) s += D0[r * 16 + k] * D0[k * 16 + q];
    DD[tid] = s;  // D_t^2
  }
  __syncthreads();

  const int fo = r;   // input feature f (row of P block at time t+dt)
  const int o = q;    // output channel
  float m[5];
  const float ut_f = uat(t, fo);

  // dt = 0:  W0 + D_t W1 + (2 D_t^2 + diag(2 c^2 u_t^2 (u_{t-1}^2 + u_{t+1}^2)) - I) W2
  {
    float acc = Wsh[fo * 16 + o];
    const float diag0 = 2.f * c * c * ut_f * ut_f *
                        ((t > 0 ? uat(t - 1, fo) * uat(t - 1, fo) : 0.f) +
                         (t < 127 ? uat(t + 1, fo) * uat(t + 1, fo) : 0.f)) - 1.f;
    #pragma unroll
    for (int fp = 0; fp < 16; fp++) {
      acc += D0[fo * 16 + fp] * Wsh[256 + fp * 16 + o];
      const float p2 = 2.f * DD[fo * 16 + fp] + ((fo == fp) ? diag0 : 0.f);
      acc += p2 * Wsh[512 + fp * 16 + o];
    }
    m[2] = acc;
  }
  // dt = +1: P1 = diag(g), P2 = 2(g(f) D_t + D_{t+1} g(f')),  g = -c u_{t+1} u_t
  if (t < 127) {
    const float gf = -c * uat(t + 1, fo) * ut_f;
    float acc = gf * Wsh[256 + fo * 16 + o];
    #pragma unroll
    for (int fp = 0; fp < 16; fp++) {
      const float gq = -c * uat(t + 1, fp) * uat(t, fp);
      const float p2 = 2.f * (gf * D0[fo * 16 + fp] + Dp[fo * 16 + fp] * gq);
      acc += p2 * Wsh[512 + fp * 16 + o];
    }
    m[3] = acc;
  } else m[3] = 0.f;
  // dt = -1
  if (t > 0) {
    const float gf = -c * uat(t - 1, fo) * ut_f;
    float acc = gf * Wsh[256 + fo * 16 + o];
    #pragma unroll
    for (int fp = 0; fp < 16; fp++) {
      const float gq = -c * uat(t - 1, fp) * uat(t, fp);
      const float p2 = 2.f * (Dm[fo * 16 + fp] * gq + gf * D0[fo * 16 + fp]);
      acc += p2 * Wsh[512 + fp * 16 + o];
    }
    m[1] = acc;
  } else m[1] = 0.f;
  // dt = +/-2: diagonal 2 c^2 u_{t+-2} u_{t+-1}^2 u_t
  m[4] = (t < 126) ? (2.f * c * c * uat(t + 2, fo) * uat(t + 1, fo) * uat(t + 1, fo) * ut_f
                      * Wsh[512 + fo * 16 + o]) : 0.f;
  m[0] = (t > 1) ? (2.f * c * c * uat(t - 2, fo) * uat(t - 1, fo) * uat(t - 1, fo) * ut_f
                    * Wsh[512 + fo * 16 + o]) : 0.f;

  #pragma unroll
  for (int d5 = 0; d5 < 5; d5++)
    wsf[((size_t)(t * 5 + d5) * 16 + fo) * 16 + o] = m[d5];
}

// ---------------- Kernel 3: out[b,t,o] = bias + sum_{dt,f} x[b,t+dt,f] M[t][dt][f][o] ----
__global__ __launch_bounds__(256) void k3_main(const float* __restrict__ x,
                                               const float* __restrict__ bias,
                                               const float* __restrict__ wsf,
                                               float* __restrict__ out) {
  const int tg = blockIdx.y, bg = blockIdx.x;
  const int t0 = tg * 16, b0 = bg * 16;
  const int tid = threadIdx.x;
  const int tl = tid >> 4, o = tid & 15;
  const int t = t0 + tl;

  float M[80];  // M column for this (t,o): [dt][f]
  {
    const float* Mt = wsf + (size_t)t * 5 * 256;
    #pragma unroll
    for (int i = 0; i < 80; i++) M[i] = Mt[i * 16 + o];
  }
  const float bo = bias[o];

  __shared__ float xs[1600];  // 4 batches x 20 rows x (16+4 pad) floats

  for (int cc = 0; cc < 4; cc++) {
    __syncthreads();
    for (int idx = tid; idx < 320; idx += 256) {
      const int cb = idx / 80, rem = idx % 80;
      const int rrow = rem >> 2, qq = rem & 3;
      int gr = t0 - 2 + rrow;
      gr = gr < 0 ? 0 : (gr > 127 ? 127 : gr);  // clamped rows hit M==0 entries
      const float4 v = *(const float4*)(x + ((size_t)(b0 + cc * 4 + cb) * 128 + gr) * 16 + qq * 4);
      *(float4*)(xs + cb * 400 + rrow * 20 + qq * 4) = v;
    }
    __syncthreads();
    #pragma unroll
    for (int cb = 0; cb < 4; cb++) {
      float acc0 = bo, acc1 = 0.f;
      #pragma unroll
      for (int dt = 0; dt < 5; dt++) {
        const float* xr = xs + cb * 400 + (tl + dt) * 20;
        const float4 xa = *(const float4*)(xr);
        const float4 xb = *(const float4*)(xr + 4);
        const float4 xc = *(const float4*)(xr + 8);
        const float4 xd = *(const float4*)(xr + 12);
        const float* Mp = M + dt * 16;
        acc0 += xa.x * Mp[0] + xa.y * Mp[1] + xa.z * Mp[2] + xa.w * Mp[3]
              + xb.x * Mp[4] + xb.y * Mp[5] + xb.z * Mp[6] + xb.w * Mp[7];
        acc1 += xc.x * Mp[8] + xc.y * Mp[9] + xc.z * Mp[10] + xc.w * Mp[11]
              + xd.x * Mp[12] + xd.y * Mp[13] + xd.z * Mp[14] + xd.w * Mp[15];
      }
      out[((size_t)(b0 + cc * 4 + cb) * 128 + t) * 16 + o] = acc0 + acc1;
    }
  }
}

extern "C" void kernel_launch(void* const* d_in, const int* in_sizes, int n_in,
                              void* d_out, int out_size, void* d_ws, size_t ws_size,
                              hipStream_t stream) {
  const float* x    = (const float*)d_in[0];  // [1024,128,16]
  const float* W    = (const float*)d_in[1];  // [3,16,16]
  const float* bias = (const float*)d_in[2];  // [16]
  const float* adj  = (const float*)d_in[3];  // [16,16]
  float* out = (float*)d_out;
  float* wsf = (float*)d_ws;  // needs 163840 floats (~656 KB)

  kA_build<<<dim3(128), dim3(256), 0, stream>>>(adj, W, wsf);
  k3_main<<<dim3(64, 8), dim3(256), 0, stream>>>(x, bias, wsf, out);
}